// Round 21
// baseline (118.855 us; speedup 1.0000x reference)
//
#include <hip/hip_runtime.h>
#include <math.h>

typedef short short8 __attribute__((ext_vector_type(8)));
typedef float f32x4  __attribute__((ext_vector_type(4)));

constexpr int Ssz = 512, Dsz = 64, Lsz = 4, Bsz = 32;
constexpr int TI = 32, TJ = 64;

// main-loop LDS: X^T double-buffered [2][64][64] bf16 (r12-verified, 16 KB)
constexpr int XTb[2] = {0, 4096};                 // short offsets
// epilogue overlay (floats; r12 layout verbatim)
constexpr int YBs = 69;                           // 69 == 5 mod 32
constexpr int YB_f = 0;                           // [32][69]
constexpr int WBs = 68;
constexpr int WB_f = YB_f + 32 * YBs;             // [64][68]
constexpr int DG_f = WB_f + 64 * WBs;             // [32] deg
constexpr int WG_f = DG_f + 32;                   // [64] gate weights
constexpr int BB_f = WG_f + 64;                   // [64] bias
constexpr int EPI_BYTES = (BB_f + 64) * 4;        // 26880 B
constexpr int SMEM_BYTES = (EPI_BYTES > 16384) ? EPI_BYTES : 16384;

__device__ __forceinline__ unsigned short f2bf(float x) {
    union { float f; unsigned u; } v; v.f = x;
    unsigned r = v.u + 0x7FFFu + ((v.u >> 16) & 1u);   // RNE
    return (unsigned short)(r >> 16);
}

__global__ __launch_bounds__(512, 4)
void rfgcn_mfma(const float* __restrict__ X,      // [B][S][D]
                const int*   __restrict__ adj,    // [L][B][S][S]
                const float* __restrict__ nw,
                const float* __restrict__ W_in,  const float* __restrict__ b_in,
                const float* __restrict__ wg_in, const float* __restrict__ bg_in,
                const float* __restrict__ W_out, const float* __restrict__ b_out,
                const float* __restrict__ wg_out,const float* __restrict__ bg_out,
                float* __restrict__ out)
{
    __shared__ __align__(16) char smem[SMEM_BYTES];
    short* sm16 = (short*)smem;
    float* smf  = (float*)smem;

    const int tid  = threadIdx.x;
    const int b    = blockIdx.y;
    const int i0   = blockIdx.x * TI;
    const int w    = tid >> 6;       // wave 0..7
    const int lane = tid & 63;
    const int dir  = w & 1;          // 0 = in (A^T), 1 = out (A)
    const int wl   = w >> 1;         // label 0..3 owned by this wave
    const int lm   = lane & 15;
    const int lg   = lane >> 4;      // k-group 0..3

    f32x4 acc[2][4];                 // [row-tile rt][e-tile nt]
    f32x4 dacc[2];
#pragma unroll
    for (int rt = 0; rt < 2; ++rt) {
#pragma unroll
        for (int nt = 0; nt < 4; ++nt) acc[rt][nt] = (f32x4){0.f, 0.f, 0.f, 0.f};
        dacc[rt] = (f32x4){0.f, 0.f, 0.f, 0.f};
    }
    const short8 ones = {(short)0x3F80, (short)0x3F80, (short)0x3F80, (short)0x3F80,
                         (short)0x3F80, (short)0x3F80, (short)0x3F80, (short)0x3F80};

    const float* Xb = X + (size_t)b * Ssz * Dsz;
    const int*   Ab = adj + ((size_t)wl * Bsz + b) * Ssz * Ssz;

    float xv[8];     // X prefetch (chunk t+1)
    int   aR[32];    // adjacency fragment prefetch

#define ADJ_LOAD(T)                                                              \
    {                                                                            \
        const int J0 = (T) * TJ;                                                 \
        if (dir == 0) {                                                          \
            _Pragma("unroll")                                                    \
            for (int rt = 0; rt < 2; ++rt)                                       \
                _Pragma("unroll")                                                \
                for (int ks = 0; ks < 2; ++ks)                                   \
                    _Pragma("unroll")                                            \
                    for (int j = 0; j < 8; ++j)                                  \
                        aR[rt * 16 + ks * 8 + j] =                               \
                            Ab[(size_t)(J0 + 32 * ks + 8 * lg + j) * Ssz + i0 + 16 * rt + lm]; \
        } else {                                                                 \
            _Pragma("unroll")                                                    \
            for (int rt = 0; rt < 2; ++rt)                                       \
                _Pragma("unroll")                                                \
                for (int ks = 0; ks < 2; ++ks) {                                 \
                    const int* p = &Ab[(size_t)(i0 + 16 * rt + lm) * Ssz + J0 + 32 * ks + 8 * lg]; \
                    const int4 q0 = *(const int4*)p;                             \
                    const int4 q1 = *(const int4*)(p + 4);                       \
                    aR[rt * 16 + ks * 8 + 0] = q0.x; aR[rt * 16 + ks * 8 + 1] = q0.y; \
                    aR[rt * 16 + ks * 8 + 2] = q0.z; aR[rt * 16 + ks * 8 + 3] = q0.w; \
                    aR[rt * 16 + ks * 8 + 4] = q1.x; aR[rt * 16 + ks * 8 + 5] = q1.y; \
                    aR[rt * 16 + ks * 8 + 6] = q1.z; aR[rt * 16 + ks * 8 + 7] = q1.w; \
                }                                                                \
        }                                                                        \
    }
#define X_LOAD(T)                                                                \
    {                                                                            \
        const int J0 = (T) * TJ;                                                 \
        _Pragma("unroll")                                                        \
        for (int s = 0; s < 8; ++s) xv[s] = Xb[(size_t)(J0 + 8 * w + s) * Dsz + lane]; \
    }
#define X_WRITE(BUF)                                                             \
    {                                                                            \
        short8 hi;                                                               \
        _Pragma("unroll")                                                        \
        for (int s = 0; s < 8; ++s) hi[s] = (short)f2bf(xv[s]);                  \
        const int g = w ^ (lane & 7);                                            \
        *(short8*)(sm16 + XTb[BUF] + lane * 64 + g * 8) = hi;                    \
    }

    // ---- pipeline prologue (r12-verified)
    X_LOAD(0)
    X_WRITE(0)
    ADJ_LOAD(0)
    X_LOAD(1)
    __syncthreads();

    for (int t = 0; t < 8; ++t) {
        const int cur = t & 1;
        short8 af[2][2];
#pragma unroll
        for (int rt = 0; rt < 2; ++rt)
#pragma unroll
            for (int ks = 0; ks < 2; ++ks)
#pragma unroll
                for (int j = 0; j < 8; ++j)
                    af[rt][ks][j] = aR[rt * 16 + ks * 8 + j] ? (short)0x3F80 : (short)0;

        if (t < 7) ADJ_LOAD(t + 1)
        if (t < 7) X_WRITE(cur ^ 1)
        if (t < 6) X_LOAD(t + 2)

#pragma unroll
        for (int ks = 0; ks < 2; ++ks) {
            short8 bh[4];
#pragma unroll
            for (int nt = 0; nt < 4; ++nt) {
                const int d = nt * 16 + lm;
                const int g = (4 * ks + lg) ^ (d & 7);
                bh[nt] = *(const short8*)(sm16 + XTb[cur] + d * 64 + g * 8);
            }
#pragma unroll
            for (int rt = 0; rt < 2; ++rt) {
#pragma unroll
                for (int nt = 0; nt < 4; ++nt)
                    acc[rt][nt] = __builtin_amdgcn_mfma_f32_16x16x32_bf16(af[rt][ks], bh[nt], acc[rt][nt], 0, 0, 0);
                dacc[rt] = __builtin_amdgcn_mfma_f32_16x16x32_bf16(af[rt][ks], ones, dacc[rt], 0, 0, 0);
            }
        }
        __syncthreads();
    }
#undef ADJ_LOAD
#undef X_LOAD
#undef X_WRITE

    // ======== epilogue: broadcast-Y layout — thread owns rows 4rg..4rg+3, col cc.
    // Per e-iter: 4 yv reads are WAVE-UNIFORM (LDS broadcast), wg uniform,
    // 1 coalesced wv read -> ~6x less LDS data movement than r12's layout.
    const int rg = tid >> 6;          // row-group 0..7 (wave-uniform)
    const int cc = tid & 63;          // column 0..63
    float fin[4];
#pragma unroll
    for (int r = 0; r < 4; ++r) fin[r] = 0.f;

#pragma unroll
    for (int l = 0; l < Lsz; ++l) {
#pragma unroll
        for (int d2 = 0; d2 < 2; ++d2) {
            if (l + d2) __syncthreads();   // first pass covered by loop-final barrier
            if (dir == d2 && wl == l) {    // owning wave writes its full Y (32 rows)
#pragma unroll
                for (int rt = 0; rt < 2; ++rt)
#pragma unroll
                    for (int nt = 0; nt < 4; ++nt)
#pragma unroll
                        for (int r = 0; r < 4; ++r)
                            smf[YB_f + (16 * rt + 4 * lg + r) * YBs + nt * 16 + lm] = acc[rt][nt][r];
                if (lm == 0)
#pragma unroll
                    for (int rt = 0; rt < 2; ++rt)
#pragma unroll
                        for (int r = 0; r < 4; ++r)
                            smf[DG_f + 16 * rt + 4 * lg + r] = dacc[rt][r];
            }
            // stage W (all threads, coalesced float4)
            const float* Wp = (d2 ? W_out : W_in) + l * Dsz * Dsz;
            {
                const int r = tid >> 3, c8 = tid & 7;
                *(float4*)&smf[WB_f + r * WBs + 8 * c8]     = *(const float4*)&Wp[r * Dsz + 8 * c8];
                *(float4*)&smf[WB_f + r * WBs + 8 * c8 + 4] = *(const float4*)&Wp[r * Dsz + 8 * c8 + 4];
            }
            const float* wgp = (d2 ? wg_out : wg_in) + l * Dsz;
            const float* bp  = (d2 ? b_out  : b_in)  + l * Dsz;
            if (tid < 64)        smf[WG_f + tid]      = wgp[tid];
            else if (tid < 128)  smf[BB_f + tid - 64] = bp[tid - 64];
            const float bgs = (d2 ? bg_out : bg_in)[l];
            __syncthreads();

            float dg[4], gate[4], tq[4];
            const float bbv = smf[BB_f + cc];
#pragma unroll
            for (int r = 0; r < 4; ++r) {
                dg[r]   = smf[DG_f + 4 * rg + r];    // uniform (broadcast)
                gate[r] = dg[r] * bgs;
                tq[r]   = dg[r] * bbv;
            }
#pragma unroll 4
            for (int e = 0; e < 64; ++e) {
                const float wv  = smf[WB_f + e * WBs + cc];   // coalesced
                const float wgv = smf[WG_f + e];              // uniform
#pragma unroll
                for (int r = 0; r < 4; ++r) {
                    const float yv = smf[YB_f + (4 * rg + r) * YBs + e];  // uniform (broadcast)
                    gate[r] += yv * wgv;
                    tq[r]   += yv * wv;
                }
            }
#pragma unroll
            for (int r = 0; r < 4; ++r) {
                const float sg = 1.f / (1.f + expf(-gate[r]));
                fin[r] += tq[r] * sg;
            }
        }
    }

    // ---- writeout: out = (X + fin) / (3*nw); 4 rows x 1 col per thread (coalesced)
    const float inv = 1.f / (3.f * nw[b]);
#pragma unroll
    for (int r = 0; r < 4; ++r) {
        const int row = i0 + 4 * rg + r;
        const float xr = Xb[(size_t)row * Dsz + cc];
        out[((size_t)b * Ssz + row) * Dsz + cc] = (xr + fin[r]) * inv;
    }
}

extern "C" void kernel_launch(void* const* d_in, const int* in_sizes, int n_in,
                              void* d_out, int out_size, void* d_ws, size_t ws_size,
                              hipStream_t stream)
{
    const float* X      = (const float*)d_in[0];
    const int*   adj    = (const int*)  d_in[1];
    const float* nw     = (const float*)d_in[2];
    const float* W_in   = (const float*)d_in[3];
    const float* b_in   = (const float*)d_in[4];
    const float* wg_in  = (const float*)d_in[5];
    const float* bg_in  = (const float*)d_in[6];
    const float* W_out  = (const float*)d_in[7];
    const float* b_out  = (const float*)d_in[8];
    const float* wg_out = (const float*)d_in[9];
    const float* bg_out = (const float*)d_in[10];
    float* out = (float*)d_out;

    dim3 grid(Ssz / TI, Bsz);   // (16, 32) = 512 blocks
    dim3 block(512);
    hipLaunchKernelGGL(rfgcn_mfma, grid, block, 0, stream,
                       X, adj, nw, W_in, b_in, wg_in, bg_in,
                       W_out, b_out, wg_out, bg_out, out);
}